// Round 1
// baseline (341.079 us; speedup 1.0000x reference)
//
#include <hip/hip_runtime.h>
#include <hip/hip_bf16.h>
#include <stdint.h>

#define LSEQ 512
#define LL   262144   // 512*512

typedef __attribute__((ext_vector_type(8))) short short8;
typedef __attribute__((ext_vector_type(4))) float f32x4;
typedef __attribute__((ext_vector_type(4))) unsigned short us4;
typedef __attribute__((ext_vector_type(8))) unsigned short us8;

static_assert(sizeof(short8) == 16, "");
static_assert(sizeof(us8) == 16, "");

__device__ inline unsigned short f2bf(float f){
  unsigned u = __builtin_bit_cast(unsigned, f);
  unsigned r = (u + 0x7fffu + ((u >> 16) & 1u)) >> 16;   // RNE
  return (unsigned short)r;
}
__device__ inline float bf2f(unsigned short s){
  return __builtin_bit_cast(float, ((unsigned)s) << 16);
}
__device__ inline float sigm(float x){ return 1.f / (1.f + __expf(-x)); }

// XOR-swizzle for LDS tiles with 256B rows (128 bf16/row): spreads 8 rows over 8 bank-quads
__device__ inline int sw256(int row, int byte_in_row){
  return row*256 + ((((byte_in_row >> 4) ^ (row & 7))) << 4) + (byte_in_row & 15);
}
// same for 128B rows (64 bf16/row)
__device__ inline int sw128(int row, int byte_in_row){
  return row*128 + ((((byte_in_row >> 4) ^ (row & 7))) << 4) + (byte_in_row & 15);
}

__device__ inline void gload16(const void* g, void* lds){
  __builtin_amdgcn_global_load_lds(
      (const __attribute__((address_space(1))) unsigned*)g,
      (__attribute__((address_space(3))) unsigned*)lds, 16, 0, 0);
}

// ---------------------------------------------------------------------------
// k0: convert weights to bf16; wg = ow * lno_g; swg = sum_d wg; swb = ow@lno_b + ob
// wbf layout: [0]=lgw [1]=lw [2]=rgw [3]=rw [4]=gw [5]=wg, each 128x128 bf16
// ---------------------------------------------------------------------------
__global__ __launch_bounds__(128) void k0_prep(
    const float* __restrict__ lw, const float* __restrict__ lgw,
    const float* __restrict__ rw, const float* __restrict__ rgw,
    const float* __restrict__ gw, const float* __restrict__ ow,
    const float* __restrict__ lnog, const float* __restrict__ lnob,
    const float* __restrict__ ob,
    unsigned short* __restrict__ wbf, float* __restrict__ swg, float* __restrict__ swb)
{
  const int dd = blockIdx.x;
  const int t  = threadIdx.x;       // 128 threads = d index
  const int idx = dd*128 + t;
  wbf[0*16384 + idx] = f2bf(lgw[idx]);
  wbf[1*16384 + idx] = f2bf(lw[idx]);
  wbf[2*16384 + idx] = f2bf(rgw[idx]);
  wbf[3*16384 + idx] = f2bf(rw[idx]);
  wbf[4*16384 + idx] = f2bf(gw[idx]);
  float o = ow[idx];
  float a = o * lnog[t];
  float b = o * lnob[t];
  wbf[5*16384 + idx] = f2bf(a);
  #pragma unroll
  for (int m = 1; m < 64; m <<= 1){ a += __shfl_xor(a, m); b += __shfl_xor(b, m); }
  __shared__ float sA[2], sB[2];
  if ((t & 63) == 0){ sA[t >> 6] = a; sB[t >> 6] = b; }
  __syncthreads();
  if (t == 0){ swg[dd] = sA[0] + sA[1]; swb[dd] = sB[0] + sB[1] + ob[dd]; }
}

// ---------------------------------------------------------------------------
// k1: LN(pair) -> p (bf16, LDS); 5 GEMMs p@W^T; epilogues:
//   left_t[h][pos]  = sigm(p@lgw+lgb)*(p@lw+lb)   (transposed, bf16)
//   right_t[h][pos] = sigm(p@rgw+rgb)*(p@rw+rb)   (transposed, bf16)
//   gate[pos][d]    = sigm(p@gw+gb)               (bf16)
// block = 128 consecutive positions (fixed i, k0..k0+127), 256 threads
// ---------------------------------------------------------------------------
__global__ __launch_bounds__(256) void k1_proj(
    const float* __restrict__ pair, const float* __restrict__ ln_g, const float* __restrict__ ln_b,
    const float* __restrict__ lb,  const float* __restrict__ lgb,
    const float* __restrict__ rb,  const float* __restrict__ rgb,
    const float* __restrict__ gb,
    const unsigned short* __restrict__ wbf,
    unsigned short* __restrict__ lt, unsigned short* __restrict__ rt,
    unsigned short* __restrict__ gate)
{
  __shared__ char p_l[32768];    // p tile [128 rows][128 bf16] swizzled
  __shared__ char wb_l[32768];   // current W [128][128] bf16 swizzled; reused as epilogue stage
  const int t = threadIdx.x;
  const int b = blockIdx.x;
  const int w = t >> 6, l = t & 63;
  const long pos0 = (long)(b >> 2)*512 + (long)(b & 3)*128;

  { // --- layernorm -> p_l ---
    const int col = (t & 31) * 4;
    const float4 g4 = *(const float4*)(ln_g + col);
    const float4 b4 = *(const float4*)(ln_b + col);
    #pragma unroll 4
    for (int pass = 0; pass < 16; ++pass){
      const int row = pass*8 + (t >> 5);
      const float4 x = *(const float4*)(pair + (pos0 + row)*128 + col);
      float s = x.x + x.y + x.z + x.w;
      float q = x.x*x.x + x.y*x.y + x.z*x.z + x.w*x.w;
      #pragma unroll
      for (int m = 1; m < 32; m <<= 1){ s += __shfl_xor(s, m); q += __shfl_xor(q, m); }
      const float mu = s * (1.f/128.f);
      const float rs = rsqrtf(q * (1.f/128.f) - mu*mu + 1e-5f);
      us4 o;
      o.x = f2bf((x.x - mu)*rs*g4.x + b4.x);
      o.y = f2bf((x.y - mu)*rs*g4.y + b4.y);
      o.z = f2bf((x.z - mu)*rs*g4.z + b4.z);
      o.w = f2bf((x.w - mu)*rs*g4.w + b4.w);
      *(us4*)(p_l + sw256(row, col*2)) = o;
    }
  }
  __syncthreads();

  auto stageW = [&](int wi){
    const char* ws = (const char*)(wbf + wi*16384);
    #pragma unroll
    for (int q = 0; q < 8; ++q){
      int P = q*4096 + t*16;                       // phys LDS byte (linear)
      gload16(ws + sw256(P >> 8, P & 255), wb_l + P); // pre-swizzled source
    }
  };

  auto zero2 = [&](f32x4 (&a)[2][8]){
    #pragma unroll
    for (int m = 0; m < 2; ++m)
      #pragma unroll
      for (int n = 0; n < 8; ++n) a[m][n] = f32x4{0.f,0.f,0.f,0.f};
  };

  auto gemm = [&](f32x4 (&acc)[2][8]){
    #pragma unroll
    for (int ks = 0; ks < 4; ++ks){
      short8 a[2];
      #pragma unroll
      for (int m = 0; m < 2; ++m){
        int row = w*32 + m*16 + (l & 15);
        a[m] = *(const short8*)(p_l + sw256(row, ks*64 + (l >> 4)*16));
      }
      #pragma unroll
      for (int n = 0; n < 8; ++n){
        int row = n*16 + (l & 15);
        short8 bb = *(const short8*)(wb_l + sw256(row, ks*64 + (l >> 4)*16));
        #pragma unroll
        for (int m = 0; m < 2; ++m)
          acc[m][n] = __builtin_amdgcn_mfma_f32_16x16x32_bf16(a[m], bb, acc[m][n], 0, 0, 0);
      }
    }
  };

  // combine two accs (gate-arm, linear-arm) and write TRANSPOSED [h][pos] bf16
  auto combineWrite = [&](f32x4 (&aG)[2][8], f32x4 (&aL)[2][8],
                          const float* gbias, const float* lbias, unsigned short* dst){
    float gv[8], lv[8];
    #pragma unroll
    for (int n = 0; n < 8; ++n){ gv[n] = gbias[n*16 + (l & 15)]; lv[n] = lbias[n*16 + (l & 15)]; }
    __syncthreads();                       // all waves done reading wb_l (GEMM)
    #pragma unroll
    for (int m = 0; m < 2; ++m){
      #pragma unroll
      for (int n = 0; n < 8; ++n){
        us4 o;
        #pragma unroll
        for (int r = 0; r < 4; ++r)
          o[r] = f2bf(sigm(aG[m][n][r] + gv[n]) * (aL[m][n][r] + lv[n]));
        int h  = n*16 + (l & 15);
        int r0 = w*32 + m*16 + (l >> 4)*4;
        *(us4*)(wb_l + sw256(h, r0*2)) = o;   // stage_t[h][r0..r0+3]
      }
    }
    __syncthreads();
    #pragma unroll
    for (int it = 0; it < 8; ++it){
      int hh = it*16 + (t >> 4), ch = t & 15;
      us8 v = *(const us8*)(wb_l + sw256(hh, ch*16));
      *(us8*)(dst + (long)hh*LL + pos0 + ch*8) = v;
    }
    __syncthreads();
  };

  f32x4 aG[2][8], aL[2][8];

  // ---- left ----
  zero2(aG); zero2(aL);
  stageW(0); __syncthreads(); gemm(aG); __syncthreads();
  stageW(1); __syncthreads(); gemm(aL);
  combineWrite(aG, aL, lgb, lb, lt);

  // ---- right ----
  zero2(aG); zero2(aL);
  stageW(2); __syncthreads(); gemm(aG); __syncthreads();
  stageW(3); __syncthreads(); gemm(aL);
  combineWrite(aG, aL, rgb, rb, rt);

  // ---- gate ----
  zero2(aG);
  stageW(4); __syncthreads(); gemm(aG);
  {
    float gv[8];
    #pragma unroll
    for (int n = 0; n < 8; ++n) gv[n] = gb[n*16 + (l & 15)];
    __syncthreads();
    #pragma unroll
    for (int m = 0; m < 2; ++m)
      #pragma unroll
      for (int n = 0; n < 8; ++n)
        #pragma unroll
        for (int r = 0; r < 4; ++r){
          int row = w*32 + m*16 + (l >> 4)*4 + r;
          int h   = n*16 + (l & 15);
          *(unsigned short*)(wb_l + sw256(row, h*2)) = f2bf(sigm(aG[m][n][r] + gv[n]));
        }
    __syncthreads();
    #pragma unroll
    for (int it = 0; it < 8; ++it){
      int row = it*16 + (t >> 4), ch = t & 15;
      us8 v = *(const us8*)(wb_l + sw256(row, ch*16));
      *(us8*)(gate + (pos0 + row)*128 + ch*8) = v;
    }
  }
}

// ---------------------------------------------------------------------------
// k2: per-channel GEMM  omm[d][i][j] = (1/512) * sum_k left_t[d][i][k]*right_t[d][j][k]
// grid 2048 = 16 tiles (128x128) x 128 channels; BK=64; 2x2 waves of 64x64
// ---------------------------------------------------------------------------
__global__ __launch_bounds__(256) void k2_tri(
    const unsigned short* __restrict__ lt, const unsigned short* __restrict__ rt,
    unsigned short* __restrict__ omm)
{
  __shared__ char smem[32768];
  char* As = smem;
  char* Bs = smem + 16384;
  const int t = threadIdx.x, b = blockIdx.x;
  const int d = b & 127, tile = b >> 7;
  const int i0 = (tile >> 2)*128, j0 = (tile & 3)*128;
  const unsigned short* Ag = lt + (long)d*LL;
  const unsigned short* Bg = rt + (long)d*LL;
  const int w = t >> 6, l = t & 63;
  const int wm = w >> 1, wn = w & 1;

  f32x4 acc[4][4];
  #pragma unroll
  for (int m = 0; m < 4; ++m)
    #pragma unroll
    for (int n = 0; n < 4; ++n) acc[m][n] = f32x4{0.f,0.f,0.f,0.f};

  for (int kt = 0; kt < 8; ++kt){
    const int k0 = kt*64;
    __syncthreads();
    #pragma unroll
    for (int q = 0; q < 4; ++q){
      int P = q*4096 + t*16;
      int row = P >> 7;
      int ls  = ((P >> 4) & 7) ^ (row & 7);        // pre-swizzled source slot
      gload16(Ag + (long)(i0 + row)*512 + k0 + ls*8, As + P);
      gload16(Bg + (long)(j0 + row)*512 + k0 + ls*8, Bs + P);
    }
    __syncthreads();
    #pragma unroll
    for (int ks = 0; ks < 2; ++ks){
      short8 a[4], bb[4];
      #pragma unroll
      for (int m = 0; m < 4; ++m){
        int row = wm*64 + m*16 + (l & 15);
        a[m] = *(const short8*)(As + sw128(row, ks*64 + (l >> 4)*16));
      }
      #pragma unroll
      for (int n = 0; n < 4; ++n){
        int row = wn*64 + n*16 + (l & 15);
        bb[n] = *(const short8*)(Bs + sw128(row, ks*64 + (l >> 4)*16));
      }
      #pragma unroll
      for (int m = 0; m < 4; ++m)
        #pragma unroll
        for (int n = 0; n < 4; ++n)
          acc[m][n] = __builtin_amdgcn_mfma_f32_16x16x32_bf16(a[m], bb[n], acc[m][n], 0, 0, 0);
    }
  }
  __syncthreads();
  // stage C (bf16) into smem for coalesced writes
  #pragma unroll
  for (int m = 0; m < 4; ++m)
    #pragma unroll
    for (int n = 0; n < 4; ++n)
      #pragma unroll
      for (int r = 0; r < 4; ++r){
        int row = wm*64 + m*16 + (l >> 4)*4 + r;
        int j   = wn*64 + n*16 + (l & 15);
        *(unsigned short*)(smem + sw256(row, j*2)) = f2bf(acc[m][n][r] * (1.f/512.f));
      }
  __syncthreads();
  #pragma unroll
  for (int it = 0; it < 8; ++it){
    int row = it*16 + (t >> 4), ch = t & 15;
    us8 v = *(const us8*)(smem + sw256(row, ch*16));
    *(us8*)(omm + (long)d*LL + (long)(i0 + row)*512 + j0 + ch*8) = v;
  }
}

// ---------------------------------------------------------------------------
// k3: folded LN2 + out-proj + gate.
//  out[i,j,dd] = gate[i,j,dd] * ( rs[j]*(S1[j][dd] - mu[j]*swg[dd]) + swb[dd] )
//  S1[j][dd] = sum_d omm[d][i][j] * wg[dd][d]   (MFMA, A = ommT via u16 gathers)
// block = (i, 128-wide j tile), 256 threads
// ---------------------------------------------------------------------------
__global__ __launch_bounds__(256) void k3_out(
    const unsigned short* __restrict__ omm, const unsigned short* __restrict__ gate,
    const unsigned short* __restrict__ wgbf,
    const float* __restrict__ swg, const float* __restrict__ swb,
    float* __restrict__ out)
{
  __shared__ char omm_l[32768];    // [d][j] bf16, plain 256B rows
  __shared__ char wg_l[32768];     // scratch (stats) then WG [dd][d] bf16 swizzled
  __shared__ float mu_s[128], rs_s[128];
  const int t = threadIdx.x;
  const int jt = blockIdx.x, i = blockIdx.y;
  const int j0 = jt*128;
  const int w = t >> 6, l = t & 63;

  { // stage omm tile + column stats partials
    const int jc = t & 15, dg = t >> 4;
    float sum[8], sq[8];
    #pragma unroll
    for (int e = 0; e < 8; ++e){ sum[e] = 0.f; sq[e] = 0.f; }
    #pragma unroll
    for (int q = 0; q < 8; ++q){
      int dd = dg + q*16;
      us8 v = *(const us8*)(omm + (long)dd*LL + (long)i*512 + j0 + jc*8);
      *(us8*)(omm_l + dd*256 + jc*16) = v;
      #pragma unroll
      for (int e = 0; e < 8; ++e){
        float f = bf2f(v[e]);
        sum[e] += f; sq[e] += f*f;
      }
    }
    float* scr = (float*)wg_l;
    #pragma unroll
    for (int e = 0; e < 8; ++e){
      scr[dg*128 + jc*8 + e]        = sum[e];
      scr[2048 + dg*128 + jc*8 + e] = sq[e];
    }
  }
  __syncthreads();
  if (t < 128){
    const float* scr = (const float*)wg_l;
    float s1 = 0.f, s2 = 0.f;
    #pragma unroll
    for (int g = 0; g < 16; ++g){ s1 += scr[g*128 + t]; s2 += scr[2048 + g*128 + t]; }
    float mu = s1 * (1.f/128.f);
    float var = s2 * (1.f/128.f) - mu*mu;
    mu_s[t] = mu;
    rs_s[t] = rsqrtf(var + 1e-5f);
  }
  __syncthreads();
  #pragma unroll
  for (int q = 0; q < 8; ++q){     // stage WG (overwrites scratch)
    int P = q*4096 + t*16;
    gload16((const char*)wgbf + sw256(P >> 8, P & 255), wg_l + P);
  }
  __syncthreads();

  f32x4 acc[2][8];
  #pragma unroll
  for (int m = 0; m < 2; ++m)
    #pragma unroll
    for (int n = 0; n < 8; ++n) acc[m][n] = f32x4{0.f,0.f,0.f,0.f};

  #pragma unroll
  for (int ks = 0; ks < 4; ++ks){
    short8 a[2];
    #pragma unroll
    for (int m = 0; m < 2; ++m){
      const int jj = w*32 + m*16 + (l & 15);
      short8 av;
      #pragma unroll
      for (int e = 0; e < 8; ++e){
        int dd = ks*32 + (l >> 4)*8 + e;
        av[e] = *(const short*)(omm_l + dd*256 + jj*2);   // ommT gather
      }
      a[m] = av;
    }
    #pragma unroll
    for (int n = 0; n < 8; ++n){
      int row = n*16 + (l & 15);
      short8 bb = *(const short8*)(wg_l + sw256(row, ks*64 + (l >> 4)*16));
      #pragma unroll
      for (int m = 0; m < 2; ++m)
        acc[m][n] = __builtin_amdgcn_mfma_f32_16x16x32_bf16(a[m], bb, acc[m][n], 0, 0, 0);
    }
  }

  float swgv[8], swbv[8];
  #pragma unroll
  for (int n = 0; n < 8; ++n){ swgv[n] = swg[n*16 + (l & 15)]; swbv[n] = swb[n*16 + (l & 15)]; }
  #pragma unroll
  for (int m = 0; m < 2; ++m){
    #pragma unroll
    for (int r = 0; r < 4; ++r){
      int j = w*32 + m*16 + (l >> 4)*4 + r;
      float mu = mu_s[j], rs = rs_s[j];
      long rowoff = ((long)i*512 + j0 + j)*128;
      #pragma unroll
      for (int n = 0; n < 8; ++n){
        int ddx = n*16 + (l & 15);
        float val = rs*(acc[m][n][r] - mu*swgv[n]) + swbv[n];
        out[rowoff + ddx] = val * bf2f(gate[rowoff + ddx]);
      }
    }
  }
}

// ---------------------------------------------------------------------------
extern "C" void kernel_launch(void* const* d_in, const int* in_sizes, int n_in,
                              void* d_out, int out_size, void* d_ws, size_t ws_size,
                              hipStream_t stream)
{
  const float* pair = (const float*)d_in[0];
  const float* ln_g = (const float*)d_in[1];
  const float* ln_b = (const float*)d_in[2];
  const float* lw   = (const float*)d_in[3];
  const float* lb   = (const float*)d_in[4];
  const float* lgw  = (const float*)d_in[5];
  const float* lgb  = (const float*)d_in[6];
  const float* rw   = (const float*)d_in[7];
  const float* rb   = (const float*)d_in[8];
  const float* rgw  = (const float*)d_in[9];
  const float* rgb  = (const float*)d_in[10];
  const float* gw   = (const float*)d_in[11];
  const float* gb   = (const float*)d_in[12];
  const float* lnog = (const float*)d_in[13];
  const float* lnob = (const float*)d_in[14];
  const float* ow   = (const float*)d_in[15];
  const float* ob   = (const float*)d_in[16];
  float* out = (float*)d_out;

  char* ws = (char*)d_ws;
  unsigned short* lt   = (unsigned short*)(ws);                   // [128][262144] bf16
  unsigned short* rt   = (unsigned short*)(ws + (1l << 26));      // [128][262144] bf16
  unsigned short* gate = (unsigned short*)(ws + (2l << 26));      // [262144][128] bf16
  unsigned short* omm  = (unsigned short*)(ws + (3l << 26));      // [128][262144] bf16
  unsigned short* wbf  = (unsigned short*)(ws + (4l << 26));      // 6 x 128x128 bf16
  float* swg = (float*)(ws + (4l << 26) + 196608);
  float* swb = swg + 128;

  k0_prep<<<dim3(128), dim3(128), 0, stream>>>(lw, lgw, rw, rgw, gw, ow, lnog, lnob, ob,
                                               wbf, swg, swb);
  k1_proj<<<dim3(2048), dim3(256), 0, stream>>>(pair, ln_g, ln_b, lb, lgb, rb, rgb, gb,
                                                wbf, lt, rt, gate);
  k2_tri<<<dim3(2048), dim3(256), 0, stream>>>(lt, rt, omm);
  k3_out<<<dim3(4, 512), dim3(256), 0, stream>>>(omm, gate, wbf + 5*16384, swg, swb, out);
}

// Round 2
// 297.924 us; speedup vs baseline: 1.1449x; 1.1449x over previous
//
#include <hip/hip_runtime.h>
#include <hip/hip_bf16.h>
#include <stdint.h>

#define LSEQ 512
#define LL   262144   // 512*512

typedef __attribute__((ext_vector_type(8))) short short8;
typedef __attribute__((ext_vector_type(4))) float f32x4;
typedef __attribute__((ext_vector_type(4))) unsigned short us4;
typedef __attribute__((ext_vector_type(8))) unsigned short us8;

static_assert(sizeof(short8) == 16, "");
static_assert(sizeof(us8) == 16, "");

__device__ inline unsigned short f2bf(float f){
  unsigned u = __builtin_bit_cast(unsigned, f);
  unsigned r = (u + 0x7fffu + ((u >> 16) & 1u)) >> 16;   // RNE
  return (unsigned short)r;
}
__device__ inline float bf2f(unsigned short s){
  return __builtin_bit_cast(float, ((unsigned)s) << 16);
}
__device__ inline float sigm(float x){ return 1.f / (1.f + __expf(-x)); }

// XOR-swizzle for LDS tiles with 256B rows (128 bf16/row)
__device__ inline int sw256(int row, int byte_in_row){
  return row*256 + ((((byte_in_row >> 4) ^ (row & 7))) << 4) + (byte_in_row & 15);
}
// same for 128B rows (64 bf16/row)
__device__ inline int sw128(int row, int byte_in_row){
  return row*128 + ((((byte_in_row >> 4) ^ (row & 7))) << 4) + (byte_in_row & 15);
}

__device__ inline void gload16(const void* g, void* lds){
  __builtin_amdgcn_global_load_lds(
      (const __attribute__((address_space(1))) unsigned*)g,
      (__attribute__((address_space(3))) unsigned*)lds, 16, 0, 0);
}

// ---------------------------------------------------------------------------
// k0: wg = ow * lno_g (bf16); swg = sum_d wg; swb = ow@lno_b + ob
// ---------------------------------------------------------------------------
__global__ __launch_bounds__(128) void k0_prep(
    const float* __restrict__ ow, const float* __restrict__ lnog,
    const float* __restrict__ lnob, const float* __restrict__ ob,
    unsigned short* __restrict__ wgbf, float* __restrict__ swg, float* __restrict__ swb)
{
  const int dd = blockIdx.x;
  const int t  = threadIdx.x;       // 128 threads = d index
  const int idx = dd*128 + t;
  float o = ow[idx];
  float a = o * lnog[t];
  float b = o * lnob[t];
  wgbf[idx] = f2bf(a);
  #pragma unroll
  for (int m = 1; m < 64; m <<= 1){ a += __shfl_xor(a, m); b += __shfl_xor(b, m); }
  __shared__ float sA[2], sB[2];
  if ((t & 63) == 0){ sA[t >> 6] = a; sB[t >> 6] = b; }
  __syncthreads();
  if (t == 0){ swg[dd] = sA[0] + sA[1]; swb[dd] = sB[0] + sB[1] + ob[dd]; }
}

// ---------------------------------------------------------------------------
// kP: pack the 5 projection weights into MFMA B-fragment order (bf16):
//   wpk[((arm*8 + n)*4 + ks)*64 + lane] = short8 where
//   elem e = W[n*16 + (lane&15)][ks*32 + (lane>>4)*8 + e]
// arms: 0=lgw 1=lw 2=rgw 3=rw 4=gw
// ---------------------------------------------------------------------------
__global__ __launch_bounds__(64) void kP_pack(
    const float* __restrict__ lgw, const float* __restrict__ lw,
    const float* __restrict__ rgw, const float* __restrict__ rw,
    const float* __restrict__ gw, short8* __restrict__ wpk)
{
  const int b = blockIdx.x;               // 0..159 = arm*32 + n*4 + ks
  const int arm = b >> 5, n = (b >> 2) & 7, ks = b & 3;
  const float* src = arm==0 ? lgw : arm==1 ? lw : arm==2 ? rgw : arm==3 ? rw : gw;
  const int l = threadIdx.x;
  const int h = n*16 + (l & 15), k0 = ks*32 + (l >> 4)*8;
  short8 v;
  #pragma unroll
  for (int e = 0; e < 8; ++e) v[e] = (short)f2bf(src[h*128 + k0 + e]);
  wpk[b*64 + l] = v;
}

// ---------------------------------------------------------------------------
// k1: LN(pair)->p (LDS); 5 GEMMs with reg-resident W frags (global L2 hits);
// epilogues write lt/rt transposed [h][pos] and gate [pos][h], all bf16.
// block = 64 positions, 256 threads (4 waves); wave w owns h in [32w,32w+32)
// ---------------------------------------------------------------------------
__global__ __launch_bounds__(256, 3) void k1_proj(
    const float* __restrict__ pair, const float* __restrict__ ln_g, const float* __restrict__ ln_b,
    const float* __restrict__ lb,  const float* __restrict__ lgb,
    const float* __restrict__ rb,  const float* __restrict__ rgb,
    const float* __restrict__ gb,
    const short8* __restrict__ wpk,
    unsigned short* __restrict__ lt, unsigned short* __restrict__ rt,
    unsigned short* __restrict__ gate)
{
  __shared__ char p_l[16384];   // p tile [64 rows][128 bf16] swizzled 256B rows
  __shared__ char epi[16384];   // epilogue staging
  const int t = threadIdx.x;
  const int w = t >> 6, l = t & 63;
  const long pos0 = (long)blockIdx.x * 64;

  { // --- layernorm -> p_l ---
    const int col = (t & 31) * 4;
    const float4 g4 = *(const float4*)(ln_g + col);
    const float4 b4 = *(const float4*)(ln_b + col);
    #pragma unroll
    for (int pass = 0; pass < 8; ++pass){
      const int row = pass*8 + (t >> 5);
      const float4 x = *(const float4*)(pair + (pos0 + row)*128 + col);
      float s = x.x + x.y + x.z + x.w;
      float q = x.x*x.x + x.y*x.y + x.z*x.z + x.w*x.w;
      #pragma unroll
      for (int m = 1; m < 32; m <<= 1){ s += __shfl_xor(s, m); q += __shfl_xor(q, m); }
      const float mu = s * (1.f/128.f);
      const float rs = rsqrtf(q * (1.f/128.f) - mu*mu + 1e-5f);
      us4 o;
      o.x = f2bf((x.x - mu)*rs*g4.x + b4.x);
      o.y = f2bf((x.y - mu)*rs*g4.y + b4.y);
      o.z = f2bf((x.z - mu)*rs*g4.z + b4.z);
      o.w = f2bf((x.w - mu)*rs*g4.w + b4.w);
      *(us4*)(p_l + sw256(row, col*2)) = o;
    }
  }
  __syncthreads();

  // A-fragments (all waves share the same 64 rows), resident for all 5 GEMMs
  short8 a[4][4];
  #pragma unroll
  for (int m = 0; m < 4; ++m)
    #pragma unroll
    for (int ks = 0; ks < 4; ++ks)
      a[m][ks] = *(const short8*)(p_l + sw256(m*16 + (l & 15), ks*64 + (l >> 4)*16));

  auto zero42 = [&](f32x4 (&acc)[4][2]){
    #pragma unroll
    for (int m = 0; m < 4; ++m){ acc[m][0] = f32x4{0,0,0,0}; acc[m][1] = f32x4{0,0,0,0}; }
  };

  // paired GEMM (gate-arm + linear-arm), W frags straight from global (L2)
  auto gemm2 = [&](int armG, int armL, f32x4 (&aG)[4][2], f32x4 (&aL)[4][2]){
    #pragma unroll
    for (int n2 = 0; n2 < 2; ++n2){
      const int n = w*2 + n2;
      short8 bg[4], blv[4];
      #pragma unroll
      for (int ks = 0; ks < 4; ++ks){
        bg[ks]  = wpk[((armG*8 + n)*4 + ks)*64 + l];
        blv[ks] = wpk[((armL*8 + n)*4 + ks)*64 + l];
      }
      #pragma unroll
      for (int ks = 0; ks < 4; ++ks)
        #pragma unroll
        for (int m = 0; m < 4; ++m){
          aG[m][n2] = __builtin_amdgcn_mfma_f32_16x16x32_bf16(a[m][ks], bg[ks],  aG[m][n2], 0, 0, 0);
          aL[m][n2] = __builtin_amdgcn_mfma_f32_16x16x32_bf16(a[m][ks], blv[ks], aL[m][n2], 0, 0, 0);
        }
    }
  };

  // combine + transposed write [h][pos]
  auto epiT = [&](f32x4 (&aG)[4][2], f32x4 (&aL)[4][2],
                  const float* __restrict__ gbias, const float* __restrict__ lbias,
                  unsigned short* __restrict__ dst){
    #pragma unroll
    for (int n2 = 0; n2 < 2; ++n2){
      const int h = w*32 + n2*16 + (l & 15);
      const float gv = gbias[h], lv = lbias[h];
      #pragma unroll
      for (int m = 0; m < 4; ++m){
        us4 o;
        #pragma unroll
        for (int r = 0; r < 4; ++r)
          o[r] = f2bf(sigm(aG[m][n2][r] + gv) * (aL[m][n2][r] + lv));
        *(us4*)(epi + sw128(h, (m*16 + (l >> 4)*4)*2)) = o;
      }
    }
    __syncthreads();
    #pragma unroll
    for (int p = 0; p < 4; ++p){
      const int hh = p*32 + (t >> 3), ch = t & 7;
      us8 v = *(const us8*)(epi + sw128(hh, ch*16));
      *(us8*)(dst + (long)hh*LL + pos0 + ch*8) = v;
    }
    __syncthreads();
  };

  f32x4 aG[4][2], aL[4][2];

  // ---- left ----
  zero42(aG); zero42(aL);
  gemm2(0, 1, aG, aL);
  epiT(aG, aL, lgb, lb, lt);

  // ---- right ----
  zero42(aG); zero42(aL);
  gemm2(2, 3, aG, aL);
  epiT(aG, aL, rgb, rb, rt);

  // ---- gate (single arm, non-transposed write [pos][h]) ----
  zero42(aG);
  #pragma unroll
  for (int n2 = 0; n2 < 2; ++n2){
    const int n = w*2 + n2;
    short8 bg[4];
    #pragma unroll
    for (int ks = 0; ks < 4; ++ks) bg[ks] = wpk[((4*8 + n)*4 + ks)*64 + l];
    #pragma unroll
    for (int ks = 0; ks < 4; ++ks)
      #pragma unroll
      for (int m = 0; m < 4; ++m)
        aG[m][n2] = __builtin_amdgcn_mfma_f32_16x16x32_bf16(a[m][ks], bg[ks], aG[m][n2], 0, 0, 0);
  }
  {
    #pragma unroll
    for (int n2 = 0; n2 < 2; ++n2){
      const int h = w*32 + n2*16 + (l & 15);
      const float gv = gb[h];
      #pragma unroll
      for (int m = 0; m < 4; ++m)
        #pragma unroll
        for (int r = 0; r < 4; ++r){
          const int pos = m*16 + (l >> 4)*4 + r;
          *(unsigned short*)(epi + sw256(pos, h*2)) = f2bf(sigm(aG[m][n2][r] + gv));
        }
    }
    __syncthreads();
    #pragma unroll
    for (int p = 0; p < 4; ++p){
      const int row = p*16 + (t >> 4), ch = t & 15;
      us8 v = *(const us8*)(epi + sw256(row, ch*16));
      *(us8*)(gate + (pos0 + row)*128 + ch*8) = v;
    }
  }
}

// ---------------------------------------------------------------------------
// k2: per-channel GEMM  omm[d][i][j] = (1/512) * sum_k left_t[d][i][k]*right_t[d][j][k]
// ---------------------------------------------------------------------------
__global__ __launch_bounds__(256) void k2_tri(
    const unsigned short* __restrict__ lt, const unsigned short* __restrict__ rt,
    unsigned short* __restrict__ omm)
{
  __shared__ char smem[32768];
  char* As = smem;
  char* Bs = smem + 16384;
  const int t = threadIdx.x, b = blockIdx.x;
  const int d = b & 127, tile = b >> 7;
  const int i0 = (tile >> 2)*128, j0 = (tile & 3)*128;
  const unsigned short* Ag = lt + (long)d*LL;
  const unsigned short* Bg = rt + (long)d*LL;
  const int w = t >> 6, l = t & 63;
  const int wm = w >> 1, wn = w & 1;

  f32x4 acc[4][4];
  #pragma unroll
  for (int m = 0; m < 4; ++m)
    #pragma unroll
    for (int n = 0; n < 4; ++n) acc[m][n] = f32x4{0.f,0.f,0.f,0.f};

  for (int kt = 0; kt < 8; ++kt){
    const int k0 = kt*64;
    __syncthreads();
    #pragma unroll
    for (int q = 0; q < 4; ++q){
      int P = q*4096 + t*16;
      int row = P >> 7;
      int ls  = ((P >> 4) & 7) ^ (row & 7);        // pre-swizzled source slot
      gload16(Ag + (long)(i0 + row)*512 + k0 + ls*8, As + P);
      gload16(Bg + (long)(j0 + row)*512 + k0 + ls*8, Bs + P);
    }
    __syncthreads();
    #pragma unroll
    for (int ks = 0; ks < 2; ++ks){
      short8 a[4], bb[4];
      #pragma unroll
      for (int m = 0; m < 4; ++m){
        int row = wm*64 + m*16 + (l & 15);
        a[m] = *(const short8*)(As + sw128(row, ks*64 + (l >> 4)*16));
      }
      #pragma unroll
      for (int n = 0; n < 4; ++n){
        int row = wn*64 + n*16 + (l & 15);
        bb[n] = *(const short8*)(Bs + sw128(row, ks*64 + (l >> 4)*16));
      }
      #pragma unroll
      for (int m = 0; m < 4; ++m)
        #pragma unroll
        for (int n = 0; n < 4; ++n)
          acc[m][n] = __builtin_amdgcn_mfma_f32_16x16x32_bf16(a[m], bb[n], acc[m][n], 0, 0, 0);
    }
  }
  __syncthreads();
  // stage C (bf16) into smem for coalesced writes
  #pragma unroll
  for (int m = 0; m < 4; ++m)
    #pragma unroll
    for (int n = 0; n < 4; ++n)
      #pragma unroll
      for (int r = 0; r < 4; ++r){
        int row = wm*64 + m*16 + (l >> 4)*4 + r;
        int j   = wn*64 + n*16 + (l & 15);
        *(unsigned short*)(smem + sw256(row, j*2)) = f2bf(acc[m][n][r] * (1.f/512.f));
      }
  __syncthreads();
  #pragma unroll
  for (int it = 0; it < 8; ++it){
    int row = it*16 + (t >> 4), ch = t & 15;
    us8 v = *(const us8*)(smem + sw256(row, ch*16));
    *(us8*)(omm + (long)d*LL + (long)(i0 + row)*512 + j0 + ch*8) = v;
  }
}

// ---------------------------------------------------------------------------
// k3: folded LN2 + out-proj + gate.
// ---------------------------------------------------------------------------
__global__ __launch_bounds__(256) void k3_out(
    const unsigned short* __restrict__ omm, const unsigned short* __restrict__ gate,
    const unsigned short* __restrict__ wgbf,
    const float* __restrict__ swg, const float* __restrict__ swb,
    float* __restrict__ out)
{
  __shared__ char omm_l[32768];    // [d][j] bf16, plain 256B rows
  __shared__ char wg_l[32768];     // scratch (stats) then WG [dd][d] bf16 swizzled
  __shared__ float mu_s[128], rs_s[128];
  const int t = threadIdx.x;
  const int jt = blockIdx.x, i = blockIdx.y;
  const int j0 = jt*128;
  const int w = t >> 6, l = t & 63;

  { // stage omm tile + column stats partials
    const int jc = t & 15, dg = t >> 4;
    float sum[8], sq[8];
    #pragma unroll
    for (int e = 0; e < 8; ++e){ sum[e] = 0.f; sq[e] = 0.f; }
    #pragma unroll
    for (int q = 0; q < 8; ++q){
      int dd = dg + q*16;
      us8 v = *(const us8*)(omm + (long)dd*LL + (long)i*512 + j0 + jc*8);
      *(us8*)(omm_l + dd*256 + jc*16) = v;
      #pragma unroll
      for (int e = 0; e < 8; ++e){
        float f = bf2f(v[e]);
        sum[e] += f; sq[e] += f*f;
      }
    }
    float* scr = (float*)wg_l;
    #pragma unroll
    for (int e = 0; e < 8; ++e){
      scr[dg*128 + jc*8 + e]        = sum[e];
      scr[2048 + dg*128 + jc*8 + e] = sq[e];
    }
  }
  __syncthreads();
  if (t < 128){
    const float* scr = (const float*)wg_l;
    float s1 = 0.f, s2 = 0.f;
    #pragma unroll
    for (int g = 0; g < 16; ++g){ s1 += scr[g*128 + t]; s2 += scr[2048 + g*128 + t]; }
    float mu = s1 * (1.f/128.f);
    float var = s2 * (1.f/128.f) - mu*mu;
    mu_s[t] = mu;
    rs_s[t] = rsqrtf(var + 1e-5f);
  }
  __syncthreads();
  #pragma unroll
  for (int q = 0; q < 8; ++q){     // stage WG (overwrites scratch)
    int P = q*4096 + t*16;
    gload16((const char*)wgbf + sw256(P >> 8, P & 255), wg_l + P);
  }
  __syncthreads();

  f32x4 acc[2][8];
  #pragma unroll
  for (int m = 0; m < 2; ++m)
    #pragma unroll
    for (int n = 0; n < 8; ++n) acc[m][n] = f32x4{0.f,0.f,0.f,0.f};

  #pragma unroll
  for (int ks = 0; ks < 4; ++ks){
    short8 a[2];
    #pragma unroll
    for (int m = 0; m < 2; ++m){
      const int jj = w*32 + m*16 + (l & 15);
      short8 av;
      #pragma unroll
      for (int e = 0; e < 8; ++e){
        int dd = ks*32 + (l >> 4)*8 + e;
        av[e] = *(const short*)(omm_l + dd*256 + jj*2);   // ommT gather
      }
      a[m] = av;
    }
    #pragma unroll
    for (int n = 0; n < 8; ++n){
      int row = n*16 + (l & 15);
      short8 bb = *(const short8*)(wg_l + sw256(row, ks*64 + (l >> 4)*16));
      #pragma unroll
      for (int m = 0; m < 2; ++m)
        acc[m][n] = __builtin_amdgcn_mfma_f32_16x16x32_bf16(a[m], bb, acc[m][n], 0, 0, 0);
    }
  }

  float swgv[8], swbv[8];
  #pragma unroll
  for (int n = 0; n < 8; ++n){ swgv[n] = swg[n*16 + (l & 15)]; swbv[n] = swb[n*16 + (l & 15)]; }
  #pragma unroll
  for (int m = 0; m < 2; ++m){
    #pragma unroll
    for (int r = 0; r < 4; ++r){
      int j = w*32 + m*16 + (l >> 4)*4 + r;
      float mu = mu_s[j], rs = rs_s[j];
      long rowoff = ((long)i*512 + j0 + j)*128;
      #pragma unroll
      for (int n = 0; n < 8; ++n){
        int ddx = n*16 + (l & 15);
        float val = rs*(acc[m][n][r] - mu*swgv[n]) + swbv[n];
        out[rowoff + ddx] = val * bf2f(gate[rowoff + ddx]);
      }
    }
  }
}

// ---------------------------------------------------------------------------
extern "C" void kernel_launch(void* const* d_in, const int* in_sizes, int n_in,
                              void* d_out, int out_size, void* d_ws, size_t ws_size,
                              hipStream_t stream)
{
  const float* pair = (const float*)d_in[0];
  const float* ln_g = (const float*)d_in[1];
  const float* ln_b = (const float*)d_in[2];
  const float* lw   = (const float*)d_in[3];
  const float* lb   = (const float*)d_in[4];
  const float* lgw  = (const float*)d_in[5];
  const float* lgb  = (const float*)d_in[6];
  const float* rw   = (const float*)d_in[7];
  const float* rb   = (const float*)d_in[8];
  const float* rgw  = (const float*)d_in[9];
  const float* rgb  = (const float*)d_in[10];
  const float* gw   = (const float*)d_in[11];
  const float* gb   = (const float*)d_in[12];
  const float* lnog = (const float*)d_in[13];
  const float* lnob = (const float*)d_in[14];
  const float* ow   = (const float*)d_in[15];
  const float* ob   = (const float*)d_in[16];
  float* out = (float*)d_out;

  char* ws = (char*)d_ws;
  unsigned short* lt   = (unsigned short*)(ws);                   // [128][262144] bf16
  unsigned short* rt   = (unsigned short*)(ws + (1l << 26));      // [128][262144] bf16
  unsigned short* gate = (unsigned short*)(ws + (2l << 26));      // [262144][128] bf16
  unsigned short* omm  = (unsigned short*)(ws + (3l << 26));      // [128][262144] bf16
  // wpk lives at the head of the omm region: consumed by k1 (before k2 writes omm)
  short8*         wpk  = (short8*)(ws + (3l << 26));              // 5*8*4*64 short8 = 320 KB
  unsigned short* wgbf = (unsigned short*)(ws + (4l << 26));      // 128x128 bf16
  float* swg = (float*)(ws + (4l << 26) + 65536);
  float* swb = swg + 128;

  k0_prep<<<dim3(128), dim3(128), 0, stream>>>(ow, lnog, lnob, ob, wgbf, swg, swb);
  kP_pack<<<dim3(160), dim3(64), 0, stream>>>(lgw, lw, rgw, rw, gw, wpk);
  k1_proj<<<dim3(4096), dim3(256), 0, stream>>>(pair, ln_g, ln_b, lb, lgb, rb, rgb, gb,
                                                wpk, lt, rt, gate);
  k2_tri<<<dim3(2048), dim3(256), 0, stream>>>(lt, rt, omm);
  k3_out<<<dim3(4, 512), dim3(256), 0, stream>>>(omm, gate, wgbf, swg, swb, out);
}